// Round 5
// baseline (483.762 us; speedup 1.0000x reference)
//
#include <hip/hip_runtime.h>

#define E_EDGES 1000000
#define BM 64
#define NBLK (E_EDGES / BM)   // 15625
#define DIN 288
#define PADA 296              // bf16 elems; row stride 592 B (16B-aligned)
#define H1DIM 128
#define PAD1 136              // 272 B row stride, 16B-aligned for b128 reads
#define NNODES 100000
#define LATENT 128

// d_ws element offsets (bf16)
#define WT1_OFF 0
#define WT2_OFF (DIN * H1DIM)                  // 36864
#define EMB_OFF (WT2_OFF + H1DIM * 64)         // 45056
#define ZB_OFF  46080                          // 92160 B, 256B-aligned
#define WS_NEED ((size_t)(ZB_OFF + NNODES * LATENT) * 2)

typedef __bf16 v8bf __attribute__((ext_vector_type(8)));
typedef __bf16 v4bf __attribute__((ext_vector_type(4)));
typedef float  v4f  __attribute__((ext_vector_type(4)));

__device__ __forceinline__ void cvt_store4(__bf16* p, float4 v) {
    v4bf o;
    o[0] = (__bf16)v.x; o[1] = (__bf16)v.y; o[2] = (__bf16)v.z; o[3] = (__bf16)v.w;
    *(v4bf*)p = o;
}

__global__ void prep_kernel(const float* __restrict__ W1, const float* __restrict__ W2,
                            const float* __restrict__ z, const float* __restrict__ embed,
                            __bf16* __restrict__ ws, int do_z) {
    int i = blockIdx.x * 256 + threadIdx.x;
    if (do_z) {
        int i4 = i * 4;
        if (i4 < NNODES * LATENT) {
            float4 v = *(const float4*)(z + i4);
            cvt_store4(ws + ZB_OFF + i4, v);
        }
    }
    if (i < DIN * H1DIM) {                    // wt1[n][k] = W1[k][n]
        int n = i / DIN, k = i - n * DIN;
        ws[WT1_OFF + i] = (__bf16)W1[k * H1DIM + n];
    }
    if (i < H1DIM * 64) {                     // wt2[n][k] = W2[k][n]
        int n = i / H1DIM, k = i - n * H1DIM;
        ws[WT2_OFF + i] = (__bf16)W2[k * 64 + n];
    }
    if (i < 13 * 32) ws[EMB_OFF + i] = (__bf16)embed[i];
}

template <bool ZBF16>
__global__ __launch_bounds__(256, 4) void fused_kernel(
    const float* __restrict__ z, const int* __restrict__ eidx,
    const int* __restrict__ bt, const float* __restrict__ embed,
    const float* __restrict__ b1, const float* __restrict__ b2,
    const float* __restrict__ W3, const float* __restrict__ b3,
    const __bf16* __restrict__ ws, float* __restrict__ out)
{
    // static LDS: 37888 + 512 + 256 + 256 + 4 = 38916 B -> 4 blocks/CU
    __shared__ __bf16 sA[BM * PADA];
    __shared__ float sb1[H1DIM];
    __shared__ float sb2[64];
    __shared__ float sw3[64];
    __shared__ float sb3s;
    __bf16* sH1 = sA;                  // alias: [64][PAD1], sA dead after GEMM1 reads

    const __bf16* wt1  = ws + WT1_OFF;
    const __bf16* wt2  = ws + WT2_OFF;
    const __bf16* embb = ws + EMB_OFF;
    const __bf16* zb   = ws + ZB_OFF;

    const int tid = threadIdx.x;
    const int e0 = blockIdx.x * BM;

    if (tid < 128) {
        sb1[tid] = b1[tid];
    } else if (tid < 192) {
        sb2[tid - 128] = b2[tid - 128];
    } else {
        int k = tid - 192;
        sw3[k] = W3[k];
        if (k == 0) sb3s = b3[0];
    }

    // ---- gather A tile: 64 rows x 288 bf16 ----
    {
        const int r = tid >> 2;
        const int j = tid & 3;
        const int e = e0 + r;
        const int isrc = eidx[e];
        const int idst = eidx[E_EDGES + e];
        const int ib   = bt[e];
        __bf16* rowp = &sA[r * PADA];
        if constexpr (ZBF16) {
            const v8bf* zs = (const v8bf*)(zb + (size_t)isrc * LATENT);
            const v8bf* zd = (const v8bf*)(zb + (size_t)idst * LATENT);
            const v8bf* em = (const v8bf*)(embb + ib * 32);
            #pragma unroll
            for (int i = 0; i < 4; ++i) { int p = i * 4 + j; *(v8bf*)(rowp + p * 8) = zs[p]; }
            #pragma unroll
            for (int i = 0; i < 4; ++i) { int p = i * 4 + j; *(v8bf*)(rowp + 128 + p * 8) = zd[p]; }
            *(v8bf*)(rowp + 256 + j * 8) = em[j];
        } else {
            const float4* zs = (const float4*)(z + (size_t)isrc * LATENT);
            const float4* zd = (const float4*)(z + (size_t)idst * LATENT);
            const float4* em = (const float4*)(embed + (size_t)ib * 32);
            #pragma unroll
            for (int i = 0; i < 8; ++i) { int p = i * 4 + j; cvt_store4(rowp + p * 4, zs[p]); }
            #pragma unroll
            for (int i = 0; i < 8; ++i) { int p = i * 4 + j; cvt_store4(rowp + 128 + p * 4, zd[p]); }
            #pragma unroll
            for (int i = 0; i < 2; ++i) { int p = i * 4 + j; cvt_store4(rowp + 256 + p * 4, em[p]); }
        }
    }
    __syncthreads();                    // B1: sA ready

    const int wave  = tid >> 6;
    const int lane  = tid & 63;
    const int quad  = lane >> 4;
    const int col16 = lane & 15;
    const int wm = wave >> 1;           // 0/1: rows wm*32..+32
    const int wn = wave & 1;            // 0/1: cols wn*64..+64 (interleaved by 4)

    // ---- GEMM1: A[64,288] x wt1^T -> H1; wave = 32 rows x 64 cols ----
    // lane's 4 cols: wn*64 + 4*col16 + {0,1,2,3} via 4 B-fragments
    v4f zero4 = {0.f, 0.f, 0.f, 0.f};
    v4f acc[2][4];
    #pragma unroll
    for (int mt = 0; mt < 2; ++mt)
        #pragma unroll
        for (int jj = 0; jj < 4; ++jj) acc[mt][jj] = zero4;

    const __bf16* w1p0 = wt1 + (size_t)(wn * 64 + 4 * col16 + 0) * DIN;
    const __bf16* w1p1 = wt1 + (size_t)(wn * 64 + 4 * col16 + 1) * DIN;
    const __bf16* w1p2 = wt1 + (size_t)(wn * 64 + 4 * col16 + 2) * DIN;
    const __bf16* w1p3 = wt1 + (size_t)(wn * 64 + 4 * col16 + 3) * DIN;
    const int arow0 = (wm * 32 + col16) * PADA;
    const int arow1 = (wm * 32 + 16 + col16) * PADA;

    #pragma unroll
    for (int ks = 0; ks < 9; ++ks) {
        int k0 = ks * 32 + quad * 8;
        v8bf a0 = *(const v8bf*)&sA[arow0 + k0];
        v8bf a1 = *(const v8bf*)&sA[arow1 + k0];
        v8bf bb0 = *(const v8bf*)&w1p0[k0];
        v8bf bb1 = *(const v8bf*)&w1p1[k0];
        v8bf bb2 = *(const v8bf*)&w1p2[k0];
        v8bf bb3 = *(const v8bf*)&w1p3[k0];
        acc[0][0] = __builtin_amdgcn_mfma_f32_16x16x32_bf16(a0, bb0, acc[0][0], 0, 0, 0);
        acc[1][0] = __builtin_amdgcn_mfma_f32_16x16x32_bf16(a1, bb0, acc[1][0], 0, 0, 0);
        acc[0][1] = __builtin_amdgcn_mfma_f32_16x16x32_bf16(a0, bb1, acc[0][1], 0, 0, 0);
        acc[1][1] = __builtin_amdgcn_mfma_f32_16x16x32_bf16(a1, bb1, acc[1][1], 0, 0, 0);
        acc[0][2] = __builtin_amdgcn_mfma_f32_16x16x32_bf16(a0, bb2, acc[0][2], 0, 0, 0);
        acc[1][2] = __builtin_amdgcn_mfma_f32_16x16x32_bf16(a1, bb2, acc[1][2], 0, 0, 0);
        acc[0][3] = __builtin_amdgcn_mfma_f32_16x16x32_bf16(a0, bb3, acc[0][3], 0, 0, 0);
        acc[1][3] = __builtin_amdgcn_mfma_f32_16x16x32_bf16(a1, bb3, acc[1][3], 0, 0, 0);
    }
    __syncthreads();                    // B2: all sA reads done (sH1 aliases sA)

    // epi1: bias + relu, pack 4 adjacent cols -> ds_write_b64
    {
        float4 bias1 = *(const float4*)&sb1[wn * 64 + 4 * col16];
        #pragma unroll
        for (int mt = 0; mt < 2; ++mt) {
            #pragma unroll
            for (int r = 0; r < 4; ++r) {
                v4bf o;
                o[0] = (__bf16)fmaxf(acc[mt][0][r] + bias1.x, 0.f);
                o[1] = (__bf16)fmaxf(acc[mt][1][r] + bias1.y, 0.f);
                o[2] = (__bf16)fmaxf(acc[mt][2][r] + bias1.z, 0.f);
                o[3] = (__bf16)fmaxf(acc[mt][3][r] + bias1.w, 0.f);
                int m = wm * 32 + mt * 16 + quad * 4 + r;
                *(v4bf*)&sH1[m * PAD1 + wn * 64 + 4 * col16] = o;
            }
        }
    }
    __syncthreads();                    // B3: sH1 ready

    // ---- GEMM2 (M-split): wave owns edges [wave*16, +16), all 64 H2 feats ----
    v4f acc2[4];
    #pragma unroll
    for (int nt = 0; nt < 4; ++nt) acc2[nt] = zero4;

    const int hrow = (wave * 16 + col16) * PAD1;
    #pragma unroll
    for (int ks = 0; ks < 4; ++ks) {
        int k0 = ks * 32 + quad * 8;
        v8bf aa = *(const v8bf*)&sH1[hrow + k0];
        #pragma unroll
        for (int nt = 0; nt < 4; ++nt) {
            v8bf bb = *(const v8bf*)&wt2[(size_t)(nt * 16 + col16) * H1DIM + k0];
            acc2[nt] = __builtin_amdgcn_mfma_f32_16x16x32_bf16(aa, bb, acc2[nt], 0, 0, 0);
        }
    }

    // ---- epi2 + GEMM3 + softplus, all in registers (H2 stays f32) ----
    {
        float b2v[4], w3v[4];
        #pragma unroll
        for (int nt = 0; nt < 4; ++nt) {
            b2v[nt] = sb2[nt * 16 + col16];
            w3v[nt] = sw3[nt * 16 + col16];
        }
        float b3v = sb3s;
        #pragma unroll
        for (int r = 0; r < 4; ++r) {
            float s = 0.f;
            #pragma unroll
            for (int nt = 0; nt < 4; ++nt)
                s += fmaxf(acc2[nt][r] + b2v[nt], 0.f) * w3v[nt];
            s += __shfl_xor(s, 1);
            s += __shfl_xor(s, 2);
            s += __shfl_xor(s, 4);
            s += __shfl_xor(s, 8);
            if (col16 == 0) {
                float x = s + b3v;
                out[e0 + wave * 16 + quad * 4 + r] = fmaxf(x, 0.f) + log1pf(expf(-fabsf(x)));
            }
        }
    }
}

extern "C" void kernel_launch(void* const* d_in, const int* in_sizes, int n_in,
                              void* d_out, int out_size, void* d_ws, size_t ws_size,
                              hipStream_t stream) {
    const float* z     = (const float*)d_in[0];
    const int*   eidx  = (const int*)d_in[1];
    const int*   btyp  = (const int*)d_in[2];
    const float* embed = (const float*)d_in[3];
    const float* W1    = (const float*)d_in[4];
    const float* b1    = (const float*)d_in[5];
    const float* W2    = (const float*)d_in[6];
    const float* b2    = (const float*)d_in[7];
    const float* W3    = (const float*)d_in[8];
    const float* b3    = (const float*)d_in[9];
    float* out = (float*)d_out;
    __bf16* ws = (__bf16*)d_ws;

    bool big_ws = (ws_size >= WS_NEED);
    if (big_ws) {
        int n4 = (NNODES * LATENT / 4 + 255) / 256;
        prep_kernel<<<n4, 256, 0, stream>>>(W1, W2, z, embed, ws, 1);
        fused_kernel<true><<<NBLK, 256, 0, stream>>>(z, eidx, btyp, embed,
                                                     b1, b2, W3, b3, ws, out);
    } else {
        prep_kernel<<<(DIN * H1DIM + 255) / 256, 256, 0, stream>>>(W1, W2, z, embed, ws, 0);
        fused_kernel<false><<<NBLK, 256, 0, stream>>>(z, eidx, btyp, embed,
                                                      b1, b2, W3, b3, ws, out);
    }
}

// Round 6
// 316.122 us; speedup vs baseline: 1.5303x; 1.5303x over previous
//
#include <hip/hip_runtime.h>

#define E_EDGES 1000000
#define BM 64
#define NBLK (E_EDGES / BM)   // 15625
#define DIN 288
#define PADA 296              // bf16 elems; row stride 592 B (16B-aligned)
#define H1DIM 128
#define PAD1 136              // 272 B row stride, 16B-aligned for b128 reads
#define NNODES 100000
#define LATENT 128

// d_ws element offsets (bf16)
#define WT1_OFF 0
#define WT2_OFF (DIN * H1DIM)                  // 36864
#define EMB_OFF (WT2_OFF + H1DIM * 64)         // 45056
#define ZB_OFF  46080                          // 92160 B, 256B-aligned
#define WS_NEED ((size_t)(ZB_OFF + NNODES * LATENT) * 2)

typedef __bf16 v8bf __attribute__((ext_vector_type(8)));
typedef __bf16 v4bf __attribute__((ext_vector_type(4)));
typedef float  v4f  __attribute__((ext_vector_type(4)));

__device__ __forceinline__ void cvt_store4(__bf16* p, float4 v) {
    v4bf o;
    o[0] = (__bf16)v.x; o[1] = (__bf16)v.y; o[2] = (__bf16)v.z; o[3] = (__bf16)v.w;
    *(v4bf*)p = o;
}

__global__ void prep_kernel(const float* __restrict__ W1, const float* __restrict__ W2,
                            const float* __restrict__ z, const float* __restrict__ embed,
                            __bf16* __restrict__ ws, int do_z) {
    int i = blockIdx.x * 256 + threadIdx.x;
    if (do_z) {
        int i4 = i * 4;
        if (i4 < NNODES * LATENT) {
            float4 v = *(const float4*)(z + i4);
            cvt_store4(ws + ZB_OFF + i4, v);
        }
    }
    if (i < DIN * H1DIM) {                    // wt1[n][k] = W1[k][n]
        int n = i / DIN, k = i - n * DIN;
        ws[WT1_OFF + i] = (__bf16)W1[k * H1DIM + n];
    }
    if (i < H1DIM * 64) {                     // wt2[f][k] = W2[k][f]
        int n = i / H1DIM, k = i - n * H1DIM;
        ws[WT2_OFF + i] = (__bf16)W2[k * 64 + n];
    }
    if (i < 13 * 32) ws[EMB_OFF + i] = (__bf16)embed[i];
}

template <bool ZBF16>
__global__ __launch_bounds__(256, 4) void fused_kernel(
    const float* __restrict__ z, const int* __restrict__ eidx,
    const int* __restrict__ bt, const float* __restrict__ embed,
    const float* __restrict__ b1, const float* __restrict__ b2,
    const float* __restrict__ W3, const float* __restrict__ b3,
    const __bf16* __restrict__ ws, float* __restrict__ out)
{
    // static LDS: 37888 + 512 + 256 + 256 + 4 = 38916 B -> 4 blocks/CU
    __shared__ __bf16 sA[BM * PADA];
    __shared__ float sb1[H1DIM];
    __shared__ float sb2[64];
    __shared__ float sw3[64];
    __shared__ float sb3s;
    __bf16* sH1 = sA;                  // alias: [64][PAD1], sA dead after GEMM1 reads

    const __bf16* wt1  = ws + WT1_OFF;
    const __bf16* wt2  = ws + WT2_OFF;
    const __bf16* embb = ws + EMB_OFF;
    const __bf16* zb   = ws + ZB_OFF;

    const int tid = threadIdx.x;
    const int e0 = blockIdx.x * BM;

    if (tid < 128) {
        sb1[tid] = b1[tid];
    } else if (tid < 192) {
        sb2[tid - 128] = b2[tid - 128];
    } else {
        int k = tid - 192;
        sw3[k] = W3[k];
        if (k == 0) sb3s = b3[0];
    }

    // ---- gather A tile: 64 rows x 288 bf16 (R4 structure, known-good) ----
    {
        const int r = tid >> 2;
        const int j = tid & 3;
        const int e = e0 + r;
        const int isrc = eidx[e];
        const int idst = eidx[E_EDGES + e];
        const int ib   = bt[e];
        __bf16* rowp = &sA[r * PADA];
        if constexpr (ZBF16) {
            const v8bf* zs = (const v8bf*)(zb + (size_t)isrc * LATENT);
            const v8bf* zd = (const v8bf*)(zb + (size_t)idst * LATENT);
            const v8bf* em = (const v8bf*)(embb + ib * 32);
            #pragma unroll
            for (int i = 0; i < 4; ++i) { int p = i * 4 + j; *(v8bf*)(rowp + p * 8) = zs[p]; }
            #pragma unroll
            for (int i = 0; i < 4; ++i) { int p = i * 4 + j; *(v8bf*)(rowp + 128 + p * 8) = zd[p]; }
            *(v8bf*)(rowp + 256 + j * 8) = em[j];
        } else {
            const float4* zs = (const float4*)(z + (size_t)isrc * LATENT);
            const float4* zd = (const float4*)(z + (size_t)idst * LATENT);
            const float4* em = (const float4*)(embed + (size_t)ib * 32);
            #pragma unroll
            for (int i = 0; i < 8; ++i) { int p = i * 4 + j; cvt_store4(rowp + p * 4, zs[p]); }
            #pragma unroll
            for (int i = 0; i < 8; ++i) { int p = i * 4 + j; cvt_store4(rowp + 128 + p * 4, zd[p]); }
            #pragma unroll
            for (int i = 0; i < 2; ++i) { int p = i * 4 + j; cvt_store4(rowp + 256 + p * 4, em[p]); }
        }
    }
    __syncthreads();                    // B1: sA ready

    const int wave  = tid >> 6;
    const int lane  = tid & 63;
    const int quad  = lane >> 4;
    const int col16 = lane & 15;

    // ---- GEMM1 (R4, known-good): wave owns N-cols [wave*32,+32), all 64 rows ----
    v4f zero4 = {0.f, 0.f, 0.f, 0.f};
    v4f acc[4][2];
    #pragma unroll
    for (int mt = 0; mt < 4; ++mt) { acc[mt][0] = zero4; acc[mt][1] = zero4; }

    const __bf16* w1p0 = wt1 + (size_t)(wave * 32 + col16) * DIN;
    const __bf16* w1p1 = wt1 + (size_t)(wave * 32 + 16 + col16) * DIN;

    #pragma unroll
    for (int ks = 0; ks < 9; ++ks) {
        int k0 = ks * 32 + quad * 8;
        v8bf a0 = *(const v8bf*)&sA[(0 * 16 + col16) * PADA + k0];
        v8bf a1 = *(const v8bf*)&sA[(1 * 16 + col16) * PADA + k0];
        v8bf a2 = *(const v8bf*)&sA[(2 * 16 + col16) * PADA + k0];
        v8bf a3 = *(const v8bf*)&sA[(3 * 16 + col16) * PADA + k0];
        v8bf bb0 = *(const v8bf*)&w1p0[k0];
        v8bf bb1 = *(const v8bf*)&w1p1[k0];
        acc[0][0] = __builtin_amdgcn_mfma_f32_16x16x32_bf16(a0, bb0, acc[0][0], 0, 0, 0);
        acc[1][0] = __builtin_amdgcn_mfma_f32_16x16x32_bf16(a1, bb0, acc[1][0], 0, 0, 0);
        acc[2][0] = __builtin_amdgcn_mfma_f32_16x16x32_bf16(a2, bb0, acc[2][0], 0, 0, 0);
        acc[3][0] = __builtin_amdgcn_mfma_f32_16x16x32_bf16(a3, bb0, acc[3][0], 0, 0, 0);
        acc[0][1] = __builtin_amdgcn_mfma_f32_16x16x32_bf16(a0, bb1, acc[0][1], 0, 0, 0);
        acc[1][1] = __builtin_amdgcn_mfma_f32_16x16x32_bf16(a1, bb1, acc[1][1], 0, 0, 0);
        acc[2][1] = __builtin_amdgcn_mfma_f32_16x16x32_bf16(a2, bb1, acc[2][1], 0, 0, 0);
        acc[3][1] = __builtin_amdgcn_mfma_f32_16x16x32_bf16(a3, bb1, acc[3][1], 0, 0, 0);
    }
    __syncthreads();                    // B2: all sA reads done (sH1 aliases sA)

    // epi1 (R4): bias + relu -> sH1 bf16 [64][PAD1]
    #pragma unroll
    for (int j = 0; j < 2; ++j) {
        int n = wave * 32 + j * 16 + col16;
        float bias = sb1[n];
        #pragma unroll
        for (int mt = 0; mt < 4; ++mt) {
            #pragma unroll
            for (int r = 0; r < 4; ++r) {
                int m = mt * 16 + quad * 4 + r;
                float h = acc[mt][j][r] + bias;
                sH1[m * PAD1 + n] = (__bf16)fmaxf(h, 0.f);
            }
        }
    }
    __syncthreads();                    // B3: sH1 ready

    // ---- GEMM2 SWAPPED: A = wt2 rows (global, L1-resident 16 KB), B = sH1 (LDS).
    // Wave owns 16 edges [wave*16,+16) as the N axis; all 64 f as the M axis.
    // D layout: col=lane&15 -> edge, row=quad*4+r (+16*nt) -> f.
    v4f acc2[4];
    #pragma unroll
    for (int nt = 0; nt < 4; ++nt) acc2[nt] = zero4;

    const int hrow = (wave * 16 + col16) * PAD1;
    #pragma unroll
    for (int ks = 0; ks < 4; ++ks) {
        int k0 = ks * 32 + quad * 8;
        v8bf bfrag = *(const v8bf*)&sH1[hrow + k0];      // B[k][e], 1 LDS read/ks
        #pragma unroll
        for (int nt = 0; nt < 4; ++nt) {
            v8bf afrag = *(const v8bf*)&wt2[(size_t)(nt * 16 + col16) * H1DIM + k0];
            acc2[nt] = __builtin_amdgcn_mfma_f32_16x16x32_bf16(afrag, bfrag, acc2[nt], 0, 0, 0);
        }
    }

    // ---- epi2 + GEMM3 + softplus in registers; reduce over f (quad axis) ----
    {
        float s = 0.f;
        #pragma unroll
        for (int nt = 0; nt < 4; ++nt) {
            #pragma unroll
            for (int r = 0; r < 4; ++r) {
                int f = nt * 16 + quad * 4 + r;
                s += fmaxf(acc2[nt][r] + sb2[f], 0.f) * sw3[f];
            }
        }
        s += __shfl_xor(s, 16);
        s += __shfl_xor(s, 32);
        if (quad == 0) {
            float x = s + sb3s;
            out[e0 + wave * 16 + col16] = fmaxf(x, 0.f) + log1pf(expf(-fabsf(x)));
        }
    }
}

extern "C" void kernel_launch(void* const* d_in, const int* in_sizes, int n_in,
                              void* d_out, int out_size, void* d_ws, size_t ws_size,
                              hipStream_t stream) {
    const float* z     = (const float*)d_in[0];
    const int*   eidx  = (const int*)d_in[1];
    const int*   btyp  = (const int*)d_in[2];
    const float* embed = (const float*)d_in[3];
    const float* W1    = (const float*)d_in[4];
    const float* b1    = (const float*)d_in[5];
    const float* W2    = (const float*)d_in[6];
    const float* b2    = (const float*)d_in[7];
    const float* W3    = (const float*)d_in[8];
    const float* b3    = (const float*)d_in[9];
    float* out = (float*)d_out;
    __bf16* ws = (__bf16*)d_ws;

    bool big_ws = (ws_size >= WS_NEED);
    if (big_ws) {
        int n4 = (NNODES * LATENT / 4 + 255) / 256;
        prep_kernel<<<n4, 256, 0, stream>>>(W1, W2, z, embed, ws, 1);
        fused_kernel<true><<<NBLK, 256, 0, stream>>>(z, eidx, btyp, embed,
                                                     b1, b2, W3, b3, ws, out);
    } else {
        prep_kernel<<<(DIN * H1DIM + 255) / 256, 256, 0, stream>>>(W1, W2, z, embed, ws, 0);
        fused_kernel<false><<<NBLK, 256, 0, stream>>>(z, eidx, btyp, embed,
                                                      b1, b2, W3, b3, ws, out);
    }
}

// Round 7
// 282.594 us; speedup vs baseline: 1.7119x; 1.1186x over previous
//
#include <hip/hip_runtime.h>

#define E_EDGES 1000000
#define BM 64
#define NBLK (E_EDGES / BM)   // 15625
#define DIN 288
#define H1DIM 128
#define PADA 168              // halfs/row of phase tile (128 or 160 cols used); 336 B, 16B-mult
#define PAD1 136              // 272 B stride, 16B-mult
#define PAD2T 68              // sH2t [feat][edge] stride
#define NNODES 100000
#define LATENT 128

// d_ws element offsets (bf16)
#define WT1_OFF 0
#define WT2_OFF (DIN * H1DIM)                  // 36864
#define EMB_OFF (WT2_OFF + H1DIM * 64)         // 45056
#define ZB_OFF  46080
#define WS_NEED ((size_t)(ZB_OFF + NNODES * LATENT) * 2)

typedef __bf16 v8bf __attribute__((ext_vector_type(8)));
typedef __bf16 v4bf __attribute__((ext_vector_type(4)));
typedef __bf16 v2bf __attribute__((ext_vector_type(2)));
typedef float  v4f  __attribute__((ext_vector_type(4)));

__device__ __forceinline__ void cvt_store4(__bf16* p, float4 v) {
    v4bf o;
    o[0] = (__bf16)v.x; o[1] = (__bf16)v.y; o[2] = (__bf16)v.z; o[3] = (__bf16)v.w;
    *(v4bf*)p = o;
}

__global__ void prep_kernel(const float* __restrict__ W1, const float* __restrict__ W2,
                            const float* __restrict__ z, const float* __restrict__ embed,
                            __bf16* __restrict__ ws, int do_z) {
    int i = blockIdx.x * 256 + threadIdx.x;
    if (do_z) {
        int i4 = i * 4;
        if (i4 < NNODES * LATENT) {
            float4 v = *(const float4*)(z + i4);
            cvt_store4(ws + ZB_OFF + i4, v);
        }
    }
    if (i < DIN * H1DIM) {                    // wt1[n][k] = W1[k][n]
        int n = i / DIN, k = i - n * DIN;
        ws[WT1_OFF + i] = (__bf16)W1[k * H1DIM + n];
    }
    if (i < H1DIM * 64) {                     // wt2[f][k] = W2[k][f]
        int n = i / H1DIM, k = i - n * H1DIM;
        ws[WT2_OFF + i] = (__bf16)W2[k * 64 + n];
    }
    if (i < 13 * 32) ws[EMB_OFF + i] = (__bf16)embed[i];
}

template <bool ZBF16>
__global__ __launch_bounds__(256, 6) void fused_kernel(
    const float* __restrict__ z, const int* __restrict__ eidx,
    const int* __restrict__ bt, const float* __restrict__ embed,
    const float* __restrict__ b1, const float* __restrict__ b2,
    const float* __restrict__ W3, const float* __restrict__ b3,
    const __bf16* __restrict__ ws, float* __restrict__ out)
{
    // Single 26,112 B buffer, phase-overlaid. 51 x 512B granules -> 6 blocks/CU.
    __shared__ __align__(16) __bf16 sbuf[13056];
    __bf16* sAh  = sbuf;               // [64][PADA]  = 10752 halfs (phases A/B)
    __bf16* sH1  = sbuf;               // [64][PAD1]  =  8704 halfs (post-GEMM1)
    __bf16* sH2t = sbuf + 8704;        // [64][PAD2T] =  4352 halfs (feat-major)

    const __bf16* wt1  = ws + WT1_OFF;
    const __bf16* wt2  = ws + WT2_OFF;
    const __bf16* embb = ws + EMB_OFF;
    const __bf16* zb   = ws + ZB_OFF;

    const int tid = threadIdx.x;
    const int e0 = blockIdx.x * BM;
    const int wave = tid >> 6, lane = tid & 63, quad = lane >> 4, col16 = lane & 15;

    // per-lane parameters straight from global (fixed lane assignment, L1-hot)
    const float2 myb1 = *(const float2*)&b1[wave * 32 + 2 * col16];
    const float  myb2 = b2[wave * 16 + col16];
    const float  myw3 = W3[wave * 16 + col16];

    // per-row gather indices (thread owns one edge row)
    const int r = tid >> 2, j = tid & 3;
    const int e = e0 + r;
    const int isrc = eidx[e];
    const int idst = eidx[E_EDGES + e];
    const int ib   = bt[e];
    __bf16* rowp = &sAh[r * PADA];

    // ---- phase A gather: src latents -> cols 0..127 ----
    if constexpr (ZBF16) {
        const v8bf* zs = (const v8bf*)(zb + (size_t)isrc * LATENT);
        #pragma unroll
        for (int i = 0; i < 4; ++i) { int p = j + 4 * i; *(v8bf*)(rowp + p * 8) = zs[p]; }
    } else {
        const float4* zs = (const float4*)(z + (size_t)isrc * LATENT);
        #pragma unroll
        for (int i = 0; i < 8; ++i) { int p = j + 4 * i; cvt_store4(rowp + p * 4, zs[p]); }
    }
    __syncthreads();                    // B1

    // ---- GEMM1 phase A: k = 0..127 ----
    // lane's cols: wave*32 + 2*col16 + {0,1}  (2 B-streams, adjacent rows)
    v4f zero4 = {0.f, 0.f, 0.f, 0.f};
    v4f acc[4][2];
    #pragma unroll
    for (int mt = 0; mt < 4; ++mt) { acc[mt][0] = zero4; acc[mt][1] = zero4; }

    const __bf16* w1p0 = wt1 + (size_t)(wave * 32 + 2 * col16) * DIN;
    const __bf16* w1p1 = w1p0 + DIN;

    #pragma unroll
    for (int ks = 0; ks < 4; ++ks) {
        int k0 = ks * 32 + quad * 8;
        v8bf a0 = *(const v8bf*)&sAh[(0 * 16 + col16) * PADA + k0];
        v8bf a1 = *(const v8bf*)&sAh[(1 * 16 + col16) * PADA + k0];
        v8bf a2 = *(const v8bf*)&sAh[(2 * 16 + col16) * PADA + k0];
        v8bf a3 = *(const v8bf*)&sAh[(3 * 16 + col16) * PADA + k0];
        v8bf bb0 = *(const v8bf*)&w1p0[k0];
        v8bf bb1 = *(const v8bf*)&w1p1[k0];
        acc[0][0] = __builtin_amdgcn_mfma_f32_16x16x32_bf16(a0, bb0, acc[0][0], 0, 0, 0);
        acc[1][0] = __builtin_amdgcn_mfma_f32_16x16x32_bf16(a1, bb0, acc[1][0], 0, 0, 0);
        acc[2][0] = __builtin_amdgcn_mfma_f32_16x16x32_bf16(a2, bb0, acc[2][0], 0, 0, 0);
        acc[3][0] = __builtin_amdgcn_mfma_f32_16x16x32_bf16(a3, bb0, acc[3][0], 0, 0, 0);
        acc[0][1] = __builtin_amdgcn_mfma_f32_16x16x32_bf16(a0, bb1, acc[0][1], 0, 0, 0);
        acc[1][1] = __builtin_amdgcn_mfma_f32_16x16x32_bf16(a1, bb1, acc[1][1], 0, 0, 0);
        acc[2][1] = __builtin_amdgcn_mfma_f32_16x16x32_bf16(a2, bb1, acc[2][1], 0, 0, 0);
        acc[3][1] = __builtin_amdgcn_mfma_f32_16x16x32_bf16(a3, bb1, acc[3][1], 0, 0, 0);
    }
    __syncthreads();                    // B2: phase-A reads done

    // ---- phase B gather: dst latents -> cols 0..127, embed -> cols 128..159 ----
    if constexpr (ZBF16) {
        const v8bf* zd = (const v8bf*)(zb + (size_t)idst * LATENT);
        const v8bf* em = (const v8bf*)(embb + ib * 32);
        #pragma unroll
        for (int i = 0; i < 5; ++i) {
            int p = j + 4 * i;                       // 0..19
            if (p < 16) *(v8bf*)(rowp + p * 8) = zd[p];
            else        *(v8bf*)(rowp + 128 + (p - 16) * 8) = em[p - 16];
        }
    } else {
        const float4* zd = (const float4*)(z + (size_t)idst * LATENT);
        const float4* em = (const float4*)(embed + (size_t)ib * 32);
        #pragma unroll
        for (int i = 0; i < 10; ++i) {
            int p = j + 4 * i;                       // 0..39
            if (p < 32) cvt_store4(rowp + p * 4, zd[p]);
            else        cvt_store4(rowp + 128 + (p - 32) * 4, em[p - 32]);
        }
    }
    __syncthreads();                    // B3

    // ---- GEMM1 phase B: k = 128..287 (160 wide, 5 k-steps) ----
    #pragma unroll
    for (int ks = 0; ks < 5; ++ks) {
        int k0 = ks * 32 + quad * 8;
        v8bf a0 = *(const v8bf*)&sAh[(0 * 16 + col16) * PADA + k0];
        v8bf a1 = *(const v8bf*)&sAh[(1 * 16 + col16) * PADA + k0];
        v8bf a2 = *(const v8bf*)&sAh[(2 * 16 + col16) * PADA + k0];
        v8bf a3 = *(const v8bf*)&sAh[(3 * 16 + col16) * PADA + k0];
        v8bf bb0 = *(const v8bf*)&w1p0[128 + k0];
        v8bf bb1 = *(const v8bf*)&w1p1[128 + k0];
        acc[0][0] = __builtin_amdgcn_mfma_f32_16x16x32_bf16(a0, bb0, acc[0][0], 0, 0, 0);
        acc[1][0] = __builtin_amdgcn_mfma_f32_16x16x32_bf16(a1, bb0, acc[1][0], 0, 0, 0);
        acc[2][0] = __builtin_amdgcn_mfma_f32_16x16x32_bf16(a2, bb0, acc[2][0], 0, 0, 0);
        acc[3][0] = __builtin_amdgcn_mfma_f32_16x16x32_bf16(a3, bb0, acc[3][0], 0, 0, 0);
        acc[0][1] = __builtin_amdgcn_mfma_f32_16x16x32_bf16(a0, bb1, acc[0][1], 0, 0, 0);
        acc[1][1] = __builtin_amdgcn_mfma_f32_16x16x32_bf16(a1, bb1, acc[1][1], 0, 0, 0);
        acc[2][1] = __builtin_amdgcn_mfma_f32_16x16x32_bf16(a2, bb1, acc[2][1], 0, 0, 0);
        acc[3][1] = __builtin_amdgcn_mfma_f32_16x16x32_bf16(a3, bb1, acc[3][1], 0, 0, 0);
    }
    __syncthreads();                    // B4: phase-B reads done; region becomes sH1/sH2t

    // ---- epi1: bias+relu, adjacent col-pair packed (ds_write_b32) ----
    #pragma unroll
    for (int mt = 0; mt < 4; ++mt) {
        #pragma unroll
        for (int rr = 0; rr < 4; ++rr) {
            int m = mt * 16 + quad * 4 + rr;
            v2bf o;
            o[0] = (__bf16)fmaxf(acc[mt][0][rr] + myb1.x, 0.f);
            o[1] = (__bf16)fmaxf(acc[mt][1][rr] + myb1.y, 0.f);
            *(v2bf*)&sH1[m * PAD1 + wave * 32 + 2 * col16] = o;
        }
    }
    __syncthreads();                    // B5: sH1 ready

    // ---- GEMM2 (R4 structure): wave owns feats wave*16+col16; A=sH1 LDS, B=wt2 (2..4 globals) ----
    v4f acc2[4];
    #pragma unroll
    for (int mt = 0; mt < 4; ++mt) acc2[mt] = zero4;

    const __bf16* w2p = wt2 + (size_t)(wave * 16 + col16) * H1DIM;
    #pragma unroll
    for (int ks = 0; ks < 4; ++ks) {
        int k0 = ks * 32 + quad * 8;
        v8bf bb = *(const v8bf*)&w2p[k0];
        #pragma unroll
        for (int mt = 0; mt < 4; ++mt) {
            v8bf aa = *(const v8bf*)&sH1[(mt * 16 + col16) * PAD1 + k0];
            acc2[mt] = __builtin_amdgcn_mfma_f32_16x16x32_bf16(aa, bb, acc2[mt], 0, 0, 0);
        }
    }

    // ---- epi2: relu * w3, packed b64 into transposed sH2t[feat][edge] ----
    {
        int feat = wave * 16 + col16;
        #pragma unroll
        for (int mt = 0; mt < 4; ++mt) {
            v4bf o;
            #pragma unroll
            for (int rr = 0; rr < 4; ++rr)
                o[rr] = (__bf16)(fmaxf(acc2[mt][rr] + myb2, 0.f) * myw3);
            *(v4bf*)&sH2t[feat * PAD2T + mt * 16 + quad * 4] = o;
        }
    }
    __syncthreads();                    // B6: sH2t ready

    // ---- GEMM3: wave-local sum over feats + softplus ----
    {
        int el = wave * 16 + col16;     // edge within tile
        float s = 0.f;
        #pragma unroll
        for (int kk = 0; kk < 16; ++kk)
            s += (float)sH2t[(quad * 16 + kk) * PAD2T + el];
        s += __shfl_xor(s, 16);
        s += __shfl_xor(s, 32);
        if (quad == 0) {
            float x = s + b3[0];
            out[e0 + el] = fmaxf(x, 0.f) + log1pf(expf(-fabsf(x)));
        }
    }
}

extern "C" void kernel_launch(void* const* d_in, const int* in_sizes, int n_in,
                              void* d_out, int out_size, void* d_ws, size_t ws_size,
                              hipStream_t stream) {
    const float* z     = (const float*)d_in[0];
    const int*   eidx  = (const int*)d_in[1];
    const int*   btyp  = (const int*)d_in[2];
    const float* embed = (const float*)d_in[3];
    const float* W1    = (const float*)d_in[4];
    const float* b1    = (const float*)d_in[5];
    const float* W2    = (const float*)d_in[6];
    const float* b2    = (const float*)d_in[7];
    const float* W3    = (const float*)d_in[8];
    const float* b3    = (const float*)d_in[9];
    float* out = (float*)d_out;
    __bf16* ws = (__bf16*)d_ws;

    bool big_ws = (ws_size >= WS_NEED);
    if (big_ws) {
        int n4 = (NNODES * LATENT / 4 + 255) / 256;
        prep_kernel<<<n4, 256, 0, stream>>>(W1, W2, z, embed, ws, 1);
        fused_kernel<true><<<NBLK, 256, 0, stream>>>(z, eidx, btyp, embed,
                                                     b1, b2, W3, b3, ws, out);
    } else {
        prep_kernel<<<(DIN * H1DIM + 255) / 256, 256, 0, stream>>>(W1, W2, z, embed, ws, 0);
        fused_kernel<false><<<NBLK, 256, 0, stream>>>(z, eidx, btyp, embed,
                                                      b1, b2, W3, b3, ws, out);
    }
}